// Round 14
// baseline (317.115 us; speedup 1.0000x reference)
//
#include <hip/hip_runtime.h>

#define NFEAT 256
#define NQ    64          // NFEAT/4 float4 quads
#define CH    512         // rows per balanced chunk (was 256)
#define BLK   256

typedef float f32x4_native __attribute__((ext_vector_type(4)));

__device__ __forceinline__ void nt_store4(float4* p, float4 v) {
    f32x4_native n; n.x = v.x; n.y = v.y; n.z = v.z; n.w = v.w;
    __builtin_nontemporal_store(n, reinterpret_cast<f32x4_native*>(p));
}

// ---------------------------------------------------------------------------
// Barrier-free scan: wave 0 (lanes 0..63) owns 2 segments/lane, does a
// 6-step shuffle inclusive scan, writes soff/sbs to LDS. One barrier total
// (was 16 Hillis-Steele barriers). Requires B <= 128 (harness: B = 128).
// ---------------------------------------------------------------------------
__device__ __forceinline__ void wave_scan(const int* __restrict__ lengths, int B,
                                          int* soff, int* sbs) {
    const int t = threadIdx.x;
    if (t < 64) {
        const int i0 = 2 * t, i1 = 2 * t + 1;
        const int a  = (i0 < B) ? lengths[i0] : 0;
        const int b  = (i1 < B) ? lengths[i1] : 0;
        const int ca = (a + CH - 1) / CH;
        const int cb = (b + CH - 1) / CH;
        const int s  = a + b;
        const int cs = ca + cb;
        int incl = s, cincl = cs;
        #pragma unroll
        for (int d = 1; d < 64; d <<= 1) {
            const int u = __shfl_up(incl,  d, 64);
            const int v = __shfl_up(cincl, d, 64);
            if (t >= d) { incl += u; cincl += v; }
        }
        const int excl  = incl  - s;
        const int cexcl = cincl - cs;
        if (i0 < B) { soff[i0] = excl;     sbs[i0] = cexcl;      }
        if (i1 < B) { soff[i1] = excl + a; sbs[i1] = cexcl + ca; }
        if (t == 63) { soff[B] = incl;     sbs[B] = cincl;       }
    }
    __syncthreads();
}

// Chunk c -> segment s with sbs[s] <= c < sbs[s+1] (parallel range test).
__device__ __forceinline__ int find_seg(const int* __restrict__ sbs, int B, int c) {
    __shared__ int sseg;
    const int t = threadIdx.x;
    if (t < B && sbs[t] <= c && c < sbs[t + 1]) sseg = t;
    __syncthreads();
    return sseg;
}

// ---------------------------------------------------------------------------
// Kernel 1: per-chunk partial sum / sum-of-squares per feature.
// Regular x loads: we WANT the tail of x resident in L3 for k_norm's
// reversed re-read. Regular psum stores: finalize reads them L2/L3-fast.
// ---------------------------------------------------------------------------
__global__ __launch_bounds__(BLK) void k_partial(const float* __restrict__ x,
                                                 const int* __restrict__ lengths,
                                                 int B,
                                                 float* __restrict__ psum,
                                                 float* __restrict__ psumsq) {
    __shared__ int soff[132], sbs[132];
    wave_scan(lengths, B, soff, sbs);

    const int bid = blockIdx.x;
    if (bid >= sbs[B]) return;

    const int seg = find_seg(sbs, B, bid);
    const int r0 = soff[seg] + (bid - sbs[seg]) * CH;
    const int r1 = min(r0 + CH, soff[seg + 1]);

    const int t  = threadIdx.x;
    const int rl = t >> 6;   // 0..3 row lane
    const int q  = t & 63;   // feature quad

    float4 sum = make_float4(0.f, 0.f, 0.f, 0.f);
    float4 sq  = make_float4(0.f, 0.f, 0.f, 0.f);

    const float4* x4 = reinterpret_cast<const float4*>(x);
    #pragma unroll 8
    for (int r = r0 + rl; r < r1; r += 4) {
        float4 v = x4[(size_t)r * NQ + q];
        sum.x += v.x; sum.y += v.y; sum.z += v.z; sum.w += v.w;
        sq.x  += v.x * v.x; sq.y += v.y * v.y; sq.z += v.z * v.z; sq.w += v.w * v.w;
    }

    __shared__ float4 lsum[4][NQ];
    __shared__ float4 lsq[4][NQ];
    lsum[rl][q] = sum;
    lsq[rl][q]  = sq;
    __syncthreads();

    if (rl == 0) {
        float4 a0 = lsum[0][q], a1 = lsum[1][q], a2 = lsum[2][q], a3 = lsum[3][q];
        float4 q0 = lsq[0][q],  q1 = lsq[1][q],  q2 = lsq[2][q],  q3 = lsq[3][q];
        float4 ts, tq;
        ts.x = a0.x + a1.x + a2.x + a3.x;  ts.y = a0.y + a1.y + a2.y + a3.y;
        ts.z = a0.z + a1.z + a2.z + a3.z;  ts.w = a0.w + a1.w + a2.w + a3.w;
        tq.x = q0.x + q1.x + q2.x + q3.x;  tq.y = q0.y + q1.y + q2.y + q3.y;
        tq.z = q0.z + q1.z + q2.z + q3.z;  tq.w = q0.w + q1.w + q2.w + q3.w;
        reinterpret_cast<float4*>(psum)[(size_t)bid * NQ + q]   = ts;
        reinterpret_cast<float4*>(psumsq)[(size_t)bid * NQ + q] = tq;
    }
}

// ---------------------------------------------------------------------------
// Kernel 2: reduce each segment's contiguous chunk range -> scale/shift.
// 4 independent accumulator pairs => 8 loads in flight.
// ---------------------------------------------------------------------------
__global__ __launch_bounds__(BLK) void k_finalize(const float* __restrict__ psum,
                                                  const float* __restrict__ psumsq,
                                                  const int* __restrict__ lengths,
                                                  int B,
                                                  const float* __restrict__ weight,
                                                  const float* __restrict__ bias,
                                                  float* __restrict__ scale,
                                                  float* __restrict__ shift) {
    __shared__ int soff[132], sbs[132];
    wave_scan(lengths, B, soff, sbs);

    const int seg = blockIdx.x;
    const int f   = threadIdx.x;
    const int b0 = sbs[seg], b1 = sbs[seg + 1];

    float s0 = 0.f, s1 = 0.f, s2 = 0.f, s3 = 0.f;
    float q0 = 0.f, q1 = 0.f, q2 = 0.f, q3 = 0.f;
    int b = b0;
    for (; b + 3 < b1; b += 4) {
        s0 += psum[(size_t)(b + 0) * NFEAT + f];  q0 += psumsq[(size_t)(b + 0) * NFEAT + f];
        s1 += psum[(size_t)(b + 1) * NFEAT + f];  q1 += psumsq[(size_t)(b + 1) * NFEAT + f];
        s2 += psum[(size_t)(b + 2) * NFEAT + f];  q2 += psumsq[(size_t)(b + 2) * NFEAT + f];
        s3 += psum[(size_t)(b + 3) * NFEAT + f];  q3 += psumsq[(size_t)(b + 3) * NFEAT + f];
    }
    for (; b < b1; ++b) {
        s0 += psum[(size_t)b * NFEAT + f];
        q0 += psumsq[(size_t)b * NFEAT + f];
    }
    const float s  = (s0 + s1) + (s2 + s3);
    const float qq = (q0 + q1) + (q2 + q3);

    const float cnt  = (float)(soff[seg + 1] - soff[seg]);
    const float m    = s / cnt;
    const float var  = fmaxf(qq / cnt - m * m, 0.f);
    const float rstd = rsqrtf(var + 1e-5f);
    const float sc   = rstd * weight[f];
    scale[(size_t)seg * NFEAT + f] = sc;
    shift[(size_t)seg * NFEAT + f] = bias[f] - m * sc;
}

// ---------------------------------------------------------------------------
// Kernel 3: normalize, chunks in REVERSE order (x tail is L3-hot from the
// stats pass); nt out stores protect that tail while it's consumed.
// ---------------------------------------------------------------------------
__global__ __launch_bounds__(BLK) void k_norm(const float* __restrict__ x,
                                              const int* __restrict__ lengths,
                                              int B,
                                              const float* __restrict__ scale,
                                              const float* __restrict__ shift,
                                              float* __restrict__ out) {
    __shared__ int soff[132], sbs[132];
    wave_scan(lengths, B, soff, sbs);

    const int nch = sbs[B];
    if ((int)blockIdx.x >= nch) return;
    const int c = nch - 1 - blockIdx.x;     // reverse: tail first (L3-hot)

    const int seg = find_seg(sbs, B, c);
    const int r0 = soff[seg] + (c - sbs[seg]) * CH;
    const int r1 = min(r0 + CH, soff[seg + 1]);

    const int t  = threadIdx.x;
    const int rl = t >> 6;
    const int q  = t & 63;

    const float4 sc = reinterpret_cast<const float4*>(scale)[(size_t)seg * NQ + q];
    const float4 sh = reinterpret_cast<const float4*>(shift)[(size_t)seg * NQ + q];

    const float4* x4 = reinterpret_cast<const float4*>(x);
    float4* o4 = reinterpret_cast<float4*>(out);
    #pragma unroll 8
    for (int r = r0 + rl; r < r1; r += 4) {
        const size_t idx = (size_t)r * NQ + q;
        float4 v = x4[idx];
        float4 o;
        o.x = v.x * sc.x + sh.x;
        o.y = v.y * sc.y + sh.y;
        o.z = v.z * sc.z + sh.z;
        o.w = v.w * sc.w + sh.w;
        nt_store4(&o4[idx], o);
    }
}

extern "C" void kernel_launch(void* const* d_in, const int* in_sizes, int n_in,
                              void* d_out, int out_size, void* d_ws, size_t ws_size,
                              hipStream_t stream) {
    const float* x       = (const float*)d_in[0];
    const int*   lengths = (const int*)d_in[1];
    const float* weight  = (const float*)d_in[2];
    const float* bias    = (const float*)d_in[3];
    float*       out     = (float*)d_out;

    const int B = in_sizes[1];               // 128
    const int N = in_sizes[0] / NFEAT;       // 524288
    const int maxCh = N / CH + B;            // chunk upper bound (1152)

    // ws layout
    char* ws = (char*)d_ws;
    float* scale  = (float*)(ws + 4096);                       // B*F
    float* shift  = scale + (size_t)B * NFEAT;                 // B*F
    float* psum   = shift + (size_t)B * NFEAT;                 // maxCh*F
    float* psumsq = psum + (size_t)maxCh * NFEAT;              // maxCh*F

    k_partial<<<maxCh, BLK, 0, stream>>>(x, lengths, B, psum, psumsq);
    k_finalize<<<B, BLK, 0, stream>>>(psum, psumsq, lengths, B, weight, bias, scale, shift);
    k_norm<<<maxCh, BLK, 0, stream>>>(x, lengths, B, scale, shift, out);
}

// Round 15
// 301.598 us; speedup vs baseline: 1.0515x; 1.0515x over previous
//
#include <hip/hip_runtime.h>

#define NFEAT 256
#define NQ    64          // NFEAT/4 float4 quads
#define CH    256         // rows per balanced chunk
#define BLK   256

typedef float f32x4_native __attribute__((ext_vector_type(4)));

__device__ __forceinline__ void nt_store4(float4* p, float4 v) {
    f32x4_native n; n.x = v.x; n.y = v.y; n.z = v.z; n.w = v.w;
    __builtin_nontemporal_store(n, reinterpret_cast<f32x4_native*>(p));
}

// ---------------------------------------------------------------------------
// In-block scan: every block derives off[0..B], bs[0..B] from lengths itself.
// 129-int coalesced load (L2-hot after the first blocks) + 8 LDS scan steps.
// No setup kernel, no ws handoff of control data (graph-replay-proof).
// ---------------------------------------------------------------------------
__device__ __forceinline__ void block_scan(const int* __restrict__ lengths, int B,
                                           int* soff, int* sbs) {
    __shared__ int L[BLK], C[BLK];
    const int t = threadIdx.x;
    int len = (t < B) ? lengths[t] : 0;
    L[t] = len;
    C[t] = (len + CH - 1) / CH;
    __syncthreads();
    #pragma unroll
    for (int d = 1; d < BLK; d <<= 1) {
        int a = L[t], c = C[t], aa = 0, cc = 0;
        if (t >= d) { aa = L[t - d]; cc = C[t - d]; }
        __syncthreads();
        L[t] = a + aa; C[t] = c + cc;
        __syncthreads();
    }
    if (t == 0) { soff[0] = 0; sbs[0] = 0; }
    if (t < B)  { soff[t + 1] = L[t]; sbs[t + 1] = C[t]; }
    __syncthreads();
}

// Chunk c -> segment s with sbs[s] <= c < sbs[s+1] (parallel range test).
__device__ __forceinline__ int find_seg(const int* __restrict__ sbs, int B, int c) {
    __shared__ int sseg;
    const int t = threadIdx.x;
    if (t < B && sbs[t] <= c && c < sbs[t + 1]) sseg = t;
    __syncthreads();
    return sseg;
}

// ---------------------------------------------------------------------------
// Kernel 1: per-chunk partial sum / sum-of-squares per feature.
// Regular x loads: we WANT the tail of x resident in L3 for k_norm's
// reversed re-read. Regular psum stores: finalize reads them L2/L3-fast.
// ---------------------------------------------------------------------------
__global__ __launch_bounds__(BLK) void k_partial(const float* __restrict__ x,
                                                 const int* __restrict__ lengths,
                                                 int B,
                                                 float* __restrict__ psum,
                                                 float* __restrict__ psumsq) {
    __shared__ int soff[132], sbs[132];
    block_scan(lengths, B, soff, sbs);

    const int bid = blockIdx.x;
    if (bid >= sbs[B]) return;

    const int seg = find_seg(sbs, B, bid);
    const int r0 = soff[seg] + (bid - sbs[seg]) * CH;
    const int r1 = min(r0 + CH, soff[seg + 1]);

    const int t  = threadIdx.x;
    const int rl = t >> 6;   // 0..3 row lane
    const int q  = t & 63;   // feature quad

    float4 sum = make_float4(0.f, 0.f, 0.f, 0.f);
    float4 sq  = make_float4(0.f, 0.f, 0.f, 0.f);

    const float4* x4 = reinterpret_cast<const float4*>(x);
    #pragma unroll 8
    for (int r = r0 + rl; r < r1; r += 4) {
        float4 v = x4[(size_t)r * NQ + q];
        sum.x += v.x; sum.y += v.y; sum.z += v.z; sum.w += v.w;
        sq.x  += v.x * v.x; sq.y += v.y * v.y; sq.z += v.z * v.z; sq.w += v.w * v.w;
    }

    __shared__ float4 lsum[4][NQ];
    __shared__ float4 lsq[4][NQ];
    lsum[rl][q] = sum;
    lsq[rl][q]  = sq;
    __syncthreads();

    if (rl == 0) {
        float4 a0 = lsum[0][q], a1 = lsum[1][q], a2 = lsum[2][q], a3 = lsum[3][q];
        float4 q0 = lsq[0][q],  q1 = lsq[1][q],  q2 = lsq[2][q],  q3 = lsq[3][q];
        float4 ts, tq;
        ts.x = a0.x + a1.x + a2.x + a3.x;  ts.y = a0.y + a1.y + a2.y + a3.y;
        ts.z = a0.z + a1.z + a2.z + a3.z;  ts.w = a0.w + a1.w + a2.w + a3.w;
        tq.x = q0.x + q1.x + q2.x + q3.x;  tq.y = q0.y + q1.y + q2.y + q3.y;
        tq.z = q0.z + q1.z + q2.z + q3.z;  tq.w = q0.w + q1.w + q2.w + q3.w;
        reinterpret_cast<float4*>(psum)[(size_t)bid * NQ + q]   = ts;
        reinterpret_cast<float4*>(psumsq)[(size_t)bid * NQ + q] = tq;
    }
}

// ---------------------------------------------------------------------------
// Kernel 2: reduce each segment's contiguous chunk range -> scale/shift.
// 4 independent accumulator pairs => 8 loads in flight.
// ---------------------------------------------------------------------------
__global__ __launch_bounds__(BLK) void k_finalize(const float* __restrict__ psum,
                                                  const float* __restrict__ psumsq,
                                                  const int* __restrict__ lengths,
                                                  int B,
                                                  const float* __restrict__ weight,
                                                  const float* __restrict__ bias,
                                                  float* __restrict__ scale,
                                                  float* __restrict__ shift) {
    __shared__ int soff[132], sbs[132];
    block_scan(lengths, B, soff, sbs);

    const int seg = blockIdx.x;
    const int f   = threadIdx.x;
    const int b0 = sbs[seg], b1 = sbs[seg + 1];

    float s0 = 0.f, s1 = 0.f, s2 = 0.f, s3 = 0.f;
    float q0 = 0.f, q1 = 0.f, q2 = 0.f, q3 = 0.f;
    int b = b0;
    for (; b + 3 < b1; b += 4) {
        s0 += psum[(size_t)(b + 0) * NFEAT + f];  q0 += psumsq[(size_t)(b + 0) * NFEAT + f];
        s1 += psum[(size_t)(b + 1) * NFEAT + f];  q1 += psumsq[(size_t)(b + 1) * NFEAT + f];
        s2 += psum[(size_t)(b + 2) * NFEAT + f];  q2 += psumsq[(size_t)(b + 2) * NFEAT + f];
        s3 += psum[(size_t)(b + 3) * NFEAT + f];  q3 += psumsq[(size_t)(b + 3) * NFEAT + f];
    }
    for (; b < b1; ++b) {
        s0 += psum[(size_t)b * NFEAT + f];
        q0 += psumsq[(size_t)b * NFEAT + f];
    }
    const float s  = (s0 + s1) + (s2 + s3);
    const float qq = (q0 + q1) + (q2 + q3);

    const float cnt  = (float)(soff[seg + 1] - soff[seg]);
    const float m    = s / cnt;
    const float var  = fmaxf(qq / cnt - m * m, 0.f);
    const float rstd = rsqrtf(var + 1e-5f);
    const float sc   = rstd * weight[f];
    scale[(size_t)seg * NFEAT + f] = sc;
    shift[(size_t)seg * NFEAT + f] = bias[f] - m * sc;
}

// ---------------------------------------------------------------------------
// Kernel 3: normalize, chunks in REVERSE order (x tail is L3-hot from the
// stats pass); nt out stores protect that tail while it's consumed.
// ---------------------------------------------------------------------------
__global__ __launch_bounds__(BLK) void k_norm(const float* __restrict__ x,
                                              const int* __restrict__ lengths,
                                              int B,
                                              const float* __restrict__ scale,
                                              const float* __restrict__ shift,
                                              float* __restrict__ out) {
    __shared__ int soff[132], sbs[132];
    block_scan(lengths, B, soff, sbs);

    const int nch = sbs[B];
    if ((int)blockIdx.x >= nch) return;
    const int c = nch - 1 - blockIdx.x;     // reverse: tail first (L3-hot)

    const int seg = find_seg(sbs, B, c);
    const int r0 = soff[seg] + (c - sbs[seg]) * CH;
    const int r1 = min(r0 + CH, soff[seg + 1]);

    const int t  = threadIdx.x;
    const int rl = t >> 6;
    const int q  = t & 63;

    const float4 sc = reinterpret_cast<const float4*>(scale)[(size_t)seg * NQ + q];
    const float4 sh = reinterpret_cast<const float4*>(shift)[(size_t)seg * NQ + q];

    const float4* x4 = reinterpret_cast<const float4*>(x);
    float4* o4 = reinterpret_cast<float4*>(out);
    #pragma unroll 8
    for (int r = r0 + rl; r < r1; r += 4) {
        const size_t idx = (size_t)r * NQ + q;
        float4 v = x4[idx];
        float4 o;
        o.x = v.x * sc.x + sh.x;
        o.y = v.y * sc.y + sh.y;
        o.z = v.z * sc.z + sh.z;
        o.w = v.w * sc.w + sh.w;
        nt_store4(&o4[idx], o);
    }
}

extern "C" void kernel_launch(void* const* d_in, const int* in_sizes, int n_in,
                              void* d_out, int out_size, void* d_ws, size_t ws_size,
                              hipStream_t stream) {
    const float* x       = (const float*)d_in[0];
    const int*   lengths = (const int*)d_in[1];
    const float* weight  = (const float*)d_in[2];
    const float* bias    = (const float*)d_in[3];
    float*       out     = (float*)d_out;

    const int B = in_sizes[1];               // 128
    const int N = in_sizes[0] / NFEAT;       // 524288
    const int maxCh = N / CH + B;            // chunk upper bound

    // ws layout
    char* ws = (char*)d_ws;
    float* scale  = (float*)(ws + 4096);                       // B*F
    float* shift  = scale + (size_t)B * NFEAT;                 // B*F
    float* psum   = shift + (size_t)B * NFEAT;                 // maxCh*F
    float* psumsq = psum + (size_t)maxCh * NFEAT;              // maxCh*F

    k_partial<<<maxCh, BLK, 0, stream>>>(x, lengths, B, psum, psumsq);
    k_finalize<<<B, BLK, 0, stream>>>(psum, psumsq, lengths, B, weight, bias, scale, shift);
    k_norm<<<maxCh, BLK, 0, stream>>>(x, lengths, B, scale, shift, out);
}